// Round 11
// baseline (83.493 us; speedup 1.0000x reference)
//
#include <hip/hip_runtime.h>
#include <stdint.h>

// Problem constants
#define CIN_  16
#define KS_   13
#define AS_   12
#define R_    12
#define KT    96            // kappa per step
#define NSTEP 26

typedef float  f32x4  __attribute__((ext_vector_type(4)));
typedef __bf16 bf16x4 __attribute__((ext_vector_type(4)));
typedef __bf16 bf16x8 __attribute__((ext_vector_type(8)));

__device__ static inline void gll16(const void* g, void* l) {
  __builtin_amdgcn_global_load_lds(
      (const __attribute__((address_space(1))) uint32_t*)g,
      (__attribute__((address_space(3))) uint32_t*)l, 16, 0, 0);
}

// ---------------------------------------------------------------------------
// Kernel 1: expand W into MFMA-fragment-ordered WmatF.
// Frag fid = kt*36 + ks*12 + mt  (1 KB each: 64 lanes x 16B).
// Lane l, elem e:  A[row = mt*16 + (l&15)][kappa = kt*96 + ks*32 + (l>>4)*8 + e]
// row=(d*12+r), kappa=(c*13+k)*12+a,
//   Wfull[d,c,r,k,a] = W[d,c, idx_map[ tivr[r,k]*12 + tir[r,a] ]].
// ---------------------------------------------------------------------------
__global__ void build_wmatf(const float* __restrict__ W,
                            const int* __restrict__ idx_map,
                            const int* __restrict__ tivr,   // [12][13]
                            const int* __restrict__ tir,    // [12][12]
                            __bf16* __restrict__ WmatF) {
  int gid  = blockIdx.x * blockDim.x + threadIdx.x;   // 0..59903 (= 936*64)
  int lane = gid & 63;
  int fid  = gid >> 6;              // 0..935
  int kt   = fid / 36;
  int rem  = fid - kt * 36;
  int ks   = rem / 12;
  int mt   = rem - ks * 12;

  int row = mt * 16 + (lane & 15);
  int d = row / R_;
  int r = row - d * R_;

  bf16x8 v;
#pragma unroll
  for (int e = 0; e < 8; ++e) {
    int kap = kt * KT + ks * 32 + (lane >> 4) * 8 + e;
    int c = kap / (KS_ * AS_);
    int t = kap - c * (KS_ * AS_);
    int k = t / AS_;
    int a = t - k * AS_;
    int s = idx_map[tivr[r * KS_ + k] * AS_ + tir[r * AS_ + a]];
    v[e] = (__bf16)W[(d * CIN_ + c) * 36 + s];
  }
  *(bf16x8*)(WmatF + (size_t)gid * 8) = v;
}

// ---------------------------------------------------------------------------
// Kernel 2: out(b,d,p,r) = Wmat(192 x 2496) @ X(2496 x [b,p])
// 512 WGs x 256 threads (4 waves), 2 WGs/CU. Each wave: 16 private p-columns,
// all 192 rows. B direct from global x; A via global_load_lds from
// fragment-ordered WmatF (L2-hot), LDS double-buffered.
// DEPTH-2 x PREFETCH (R9 post-mortem: kernel is latency-limited, not
// BW-limited -- warm-L3 x ran 60us vs cold 82us at equal combined BW).
// Three rotating B register sets keep ~96 KB/CU of x in flight at all
// times (Little's law needs ~41 KB at loaded HBM latency). Per half-step:
// vmcnt(6) drains only the glls; B(t+2) rides across the barrier.
// ---------------------------------------------------------------------------
__global__ __launch_bounds__(256, 2)
void s2conv(const float* __restrict__ x,
            const __bf16* __restrict__ WmatF,
            float* __restrict__ out) {
  __shared__ __bf16 As[2][36 * 512];   // 2 x 36 frags x 1 KB = 72 KB

  const int tid  = threadIdx.x;
  const int lane = tid & 63;
  const int wave = tid >> 6;        // 0..3 -> 16-col group
  const int l15  = lane & 15;
  const int l4   = lane >> 4;

  const int wg = blockIdx.x;        // 0..511
  const int b  = wg >> 6;           // 0..7
  const int p0 = (wg & 63) << 6;    // 64-col tile
  const int p  = p0 + wave * 16 + l15;   // this thread's private column

  // B-load byte offsets: kappa_local = ks*32 + l4*8 + h*4 -> (ck, a);
  // 4 consecutive floats, never crosses ck (a%4==0).
  int voff[3][2];
#pragma unroll
  for (int ks = 0; ks < 3; ++ks)
#pragma unroll
    for (int h = 0; h < 2; ++h) {
      int kl = ks * 32 + l4 * 8 + h * 4;
      int ck = kl / 12, a = kl - ck * 12;
      voff[ks][h] = (ck * 49152 + p * 12 + a) * 4;
    }
  const char* xb = (const char*)(x + (size_t)b * 208 * 49152);

  f32x4 acc[12];
#pragma unroll
  for (int i = 0; i < 12; ++i) acc[i] = f32x4{0.f, 0.f, 0.f, 0.f};

  // gll frags: 36 per WG / 4 waves = 9 each, no duplicates.
  const int fr0 = wave * 9;

  auto stageA = [&](int kt, int buf) {
    const char* gk = (const char*)WmatF + (size_t)kt * 36864;
    char* lb = (char*)&As[buf][0];
#pragma unroll
    for (int f = 0; f < 9; ++f)
      gll16(gk + (fr0 + f) * 1024 + lane * 16, lb + (fr0 + f) * 1024);
  };

  auto loadB = [&](int kt, f32x4 (&bs)[3][2]) {
    const char* xk = xb + (size_t)kt * (8 * 49152 * 4);
#pragma unroll
    for (int ks = 0; ks < 3; ++ks)
#pragma unroll
      for (int h = 0; h < 2; ++h)
        bs[ks][h] = *(const f32x4*)(xk + voff[ks][h]);
  };

  auto mfma_phase = [&](int buf, f32x4 (&bs)[3][2]) {
    const char* lb = (const char*)&As[buf][0];
#pragma unroll
    for (int ks = 0; ks < 3; ++ks) {
      bf16x4 lo = __builtin_convertvector(bs[ks][0], bf16x4);
      bf16x4 hi = __builtin_convertvector(bs[ks][1], bf16x4);
      bf16x8 bfr = __builtin_shufflevector(lo, hi, 0, 1, 2, 3, 4, 5, 6, 7);
#pragma unroll
      for (int mt = 0; mt < 12; ++mt) {
        bf16x8 af = *(const bf16x8*)(lb + (ks * 12 + mt) * 1024 + lane * 16);
        acc[mt] = __builtin_amdgcn_mfma_f32_16x16x32_bf16(af, bfr, acc[mt],
                                                          0, 0, 0);
      }
    }
  };

  // One half-step: stage A(t+1) into buf^1; issue B(t+2) (depth-2); compute
  // tile t from buf + Scur; drain glls only (vmcnt(6): B(t+2) stays out).
  auto half = [&](int t, int buf, f32x4 (&Scur)[3][2], f32x4 (&Sn2)[3][2]) {
    stageA(t + 1, buf ^ 1);
    __builtin_amdgcn_sched_barrier(0);
    loadB(t + 2, Sn2);
    __builtin_amdgcn_sched_barrier(0);
    mfma_phase(buf, Scur);
    asm volatile("s_waitcnt vmcnt(6)" ::: "memory");
    __builtin_amdgcn_s_barrier();
  };

  f32x4 bs0[3][2], bs1[3][2], bs2[3][2];

  // ---- prologue: A(0) + B(0) + B(1) ----------------------------------------
  stageA(0, 0);
  __builtin_amdgcn_sched_barrier(0);
  loadB(0, bs0);
  loadB(1, bs1);
  __builtin_amdgcn_sched_barrier(0);
  asm volatile("s_waitcnt vmcnt(12)" ::: "memory");  // glls done; B0,B1 fly
  __builtin_amdgcn_s_barrier();

  // ---- main loop: tiles 0..23 (set = t%3, buf = t%2), loads up to B(25) ----
#pragma unroll 1
  for (int tb = 0; tb < 24; tb += 6) {
    half(tb + 0, 0, bs0, bs2);
    half(tb + 1, 1, bs1, bs0);
    half(tb + 2, 0, bs2, bs1);
    half(tb + 3, 1, bs0, bs2);
    half(tb + 4, 0, bs1, bs0);
    half(tb + 5, 1, bs2, bs1);
  }

  // ---- tail: tiles 24 (buf0, bs0) and 25 (buf1, bs1), no new loads ---------
  stageA(25, 1);
  __builtin_amdgcn_sched_barrier(0);
  mfma_phase(0, bs0);
  asm volatile("s_waitcnt vmcnt(0)" ::: "memory");   // epilogue: full drain ok
  __builtin_amdgcn_s_barrier();
  mfma_phase(1, bs1);

  // ---- epilogue: col=l15 (=p), row = mt*16 + l4*4 + reg --------------------
#pragma unroll
  for (int mt = 0; mt < 12; ++mt) {
    int mrow0 = mt * 16 + l4 * 4;        // r0 in {0,4,8} -> same d
    int d  = mrow0 / 12;
    int r0 = mrow0 - d * 12;
    float* dst = out + (size_t)((b * 16 + d) * 4096 + p) * 12 + r0;
    *(f32x4*)dst = acc[mt];              // 16B aligned
  }
}

// ---------------------------------------------------------------------------
extern "C" void kernel_launch(void* const* d_in, const int* in_sizes, int n_in,
                              void* d_out, int out_size, void* d_ws, size_t ws_size,
                              hipStream_t stream) {
  const float* x       = (const float*)d_in[0];  // (8,16,13,4096,12) f32
  const float* W       = (const float*)d_in[1];  // (16,16,36) f32
  const int*   idx_map = (const int*)d_in[2];    // (156,)
  const int*   tivr    = (const int*)d_in[3];    // (12,13)
  const int*   tir     = (const int*)d_in[4];    // (12,12)
  float*       out     = (float*)d_out;          // (8,16,4096,12) f32
  __bf16*      WmatF   = (__bf16*)d_ws;          // 936 KB, fragment-ordered

  build_wmatf<<<dim3(117), dim3(512), 0, stream>>>(W, idx_map, tivr, tir, WmatF);
  s2conv<<<dim3(512), dim3(256), 0, stream>>>(x, WmatF, out);
}

// Round 12
// 80.991 us; speedup vs baseline: 1.0309x; 1.0309x over previous
//
#include <hip/hip_runtime.h>
#include <stdint.h>

// Problem constants
#define CIN_  16
#define KS_   13
#define AS_   12
#define R_    12
#define KT    96            // kappa per step
#define NSTEP 26
#define LDP   104           // X LDS pitch (96 + 8 pad)

typedef float  f32x4  __attribute__((ext_vector_type(4)));
typedef __bf16 bf16x4 __attribute__((ext_vector_type(4)));
typedef __bf16 bf16x8 __attribute__((ext_vector_type(8)));

// ---------------------------------------------------------------------------
// Kernel 1: expand W into per-wave-grouped MFMA-fragment order.
// fid = kt*36 + w*9 + (mtl*3 + ks), global mt = w*3 + mtl (1 KB frags).
// Lane l, elem e: A[row = mt*16 + (l&15)][kappa = kt*96 + ks*32 + (l>>4)*8 + e]
// row=(d*12+r), kappa=(c*13+k)*12+a,
//   Wfull[d,c,r,k,a] = W[d,c, idx_map[ tivr[r,k]*12 + tir[r,a] ]].
// Per (kt, wave): 9 contiguous KB -> 9 coalesced dwordx4 per wave per step.
// ---------------------------------------------------------------------------
__global__ void build_wmatf(const float* __restrict__ W,
                            const int* __restrict__ idx_map,
                            const int* __restrict__ tivr,   // [12][13]
                            const int* __restrict__ tir,    // [12][12]
                            __bf16* __restrict__ WmatF) {
  int gid  = blockIdx.x * blockDim.x + threadIdx.x;   // 0..59903 (= 936*64)
  int lane = gid & 63;
  int fid  = gid >> 6;              // 0..935
  int kt   = fid / 36;
  int rem  = fid - kt * 36;
  int w    = rem / 9;
  int sub  = rem - w * 9;
  int mtl  = sub / 3;
  int ks   = sub - mtl * 3;
  int mt   = w * 3 + mtl;

  int row = mt * 16 + (lane & 15);
  int d = row / R_;
  int r = row - d * R_;

  bf16x8 v;
#pragma unroll
  for (int e = 0; e < 8; ++e) {
    int kap = kt * KT + ks * 32 + (lane >> 4) * 8 + e;
    int c = kap / (KS_ * AS_);
    int t = kap - c * (KS_ * AS_);
    int k = t / AS_;
    int a = t - k * AS_;
    int s = idx_map[tivr[r * KS_ + k] * AS_ + tir[r * AS_ + a]];
    v[e] = (__bf16)W[(d * CIN_ + c) * 36 + s];
  }
  *(bf16x8*)(WmatF + (size_t)gid * 8) = v;
}

// ---------------------------------------------------------------------------
// Kernel 2: out(b,d,p,r) = Wmat(192 x 2496) @ X(2496 x [b,p])
// 512 WGs x 256 threads (4 waves), 2 WGs/CU. R10 post-mortem: LDS phase
// (~2900 cyc/CU/step) serialized with HBM (4670) -> shrink LDS phase 6x:
//   A: REGISTERS, straight from L2-resident WmatF (wave owns 48 unique rows,
//      9 contiguous dwordx4/step, double-buffered reg sets).
//   X: LDS bf16 (12 KB write + 12 KB read per WG per step), double-buffered.
// x read exactly once (coalesced f32x4); one lgkmcnt(0)+s_barrier per step;
// all loads unconditional -> counted vmcnt everywhere.
// ---------------------------------------------------------------------------
__global__ __launch_bounds__(256, 2)
void s2conv(const float* __restrict__ x,
            const __bf16* __restrict__ WmatF,
            float* __restrict__ out) {
  __shared__ __bf16 Xs[2][64][LDP];   // 2 x 13.3 KB = 26.6 KB

  const int tid  = threadIdx.x;
  const int lane = tid & 63;
  const int wave = tid >> 6;        // 0..3: owns rows wave*48..wave*48+47
  const int l15  = lane & 15;
  const int l4   = lane >> 4;

  const int wg = blockIdx.x;        // 0..511
  const int b  = wg >> 6;           // 0..7
  const int p0 = (wg & 63) << 6;    // 64-col tile

  f32x4 acc[3][4];
#pragma unroll
  for (int i = 0; i < 3; ++i)
#pragma unroll
    for (int j = 0; j < 4; ++j)
      acc[i][j] = f32x4{0.f, 0.f, 0.f, 0.f};

  // ---- A: 9 frags/step from L2 (contiguous 9 KB per wave) ------------------
  const char* aBase = (const char*)WmatF + (size_t)wave * 9216 + lane * 16;
  auto loadA = [&](int kt, bf16x8 (&af)[9]) {
    const char* gk = aBase + (size_t)kt * 36864;
#pragma unroll
    for (int f = 0; f < 9; ++f)
      af[f] = *(const bf16x8*)(gk + f * 1024);
  };

  // ---- x: 6 coalesced f32x4 per thread per step ----------------------------
  // thread chunk it = h*3+j: ck_local = wave*2+h, f4i = j*64+lane (0..191)
  const char* xb = (const char*)x + ((size_t)b * 208) * 49152 * 4
                   + (size_t)p0 * 48;
  auto load_x = [&](int kt, f32x4 (&st)[6]) {
#pragma unroll
    for (int h = 0; h < 2; ++h) {
      const char* bp = xb + ((size_t)(kt * 8 + wave * 2 + h)) * (49152 * 4);
#pragma unroll
      for (int j = 0; j < 3; ++j)
        st[h * 3 + j] = *(const f32x4*)(bp + (j * 64 + lane) * 16);
    }
  };

  auto write_X = [&](int buf, f32x4 (&st)[6]) {
    char* xsb = (char*)&Xs[buf][0][0];
#pragma unroll
    for (int h = 0; h < 2; ++h) {
      int ck12 = (wave * 2 + h) * 12;
#pragma unroll
      for (int j = 0; j < 3; ++j) {
        int f4i = j * 64 + lane;
        int pl  = f4i / 3;
        int a   = (f4i - pl * 3) * 4;          // 0,4,8
        bf16x4 v = __builtin_convertvector(st[h * 3 + j], bf16x4);
        *(bf16x4*)(xsb + (pl * LDP + ck12 + a) * 2) = v;
      }
    }
  };

  auto mfma_phase = [&](int buf, bf16x8 (&af)[9]) {
    const __bf16* xsb = &Xs[buf][0][0];
#pragma unroll
    for (int ks = 0; ks < 3; ++ks) {
      bf16x8 bfr[4];
#pragma unroll
      for (int nt = 0; nt < 4; ++nt)
        bfr[nt] = *(const bf16x8*)(xsb + (nt * 16 + l15) * LDP
                                       + ks * 32 + l4 * 8);
#pragma unroll
      for (int mtl = 0; mtl < 3; ++mtl)
#pragma unroll
        for (int nt = 0; nt < 4; ++nt)
          acc[mtl][nt] = __builtin_amdgcn_mfma_f32_16x16x32_bf16(
              af[mtl * 3 + ks], bfr[nt], acc[mtl][nt], 0, 0, 0);
    }
  };

  auto barrier = [&]() {
    asm volatile("s_waitcnt lgkmcnt(0)" ::: "memory");  // ds_writes visible
    __builtin_amdgcn_s_barrier();                        // no vmcnt drain
  };

  // ---- prologue ------------------------------------------------------------
  f32x4  s0[6], s1[6];
  bf16x8 aE[9], aO[9];
  load_x(0, s0);
  load_x(1, s1);
  loadA(0, aE);
  __builtin_amdgcn_sched_barrier(0);
  write_X(0, s0);
  barrier();

  // ---- main loop: steps 0..23 (12 x 2), all loads unconditional ------------
#pragma unroll 1
  for (int t = 0; t < 24; t += 2) {
    // even step t (buf 0): compute A(t)=aE; stage X(t+1); fetch x(t+2),A(t+1)
    load_x(t + 2, s0);
    loadA(t + 1, aO);
    __builtin_amdgcn_sched_barrier(0);
    write_X(1, s1);
    mfma_phase(0, aE);
    barrier();

    // odd step t+1 (buf 1)
    load_x(t + 3, s1);
    loadA(t + 2, aE);
    __builtin_amdgcn_sched_barrier(0);
    write_X(0, s0);
    mfma_phase(1, aO);
    barrier();
  }

  // ---- tail: step 24 (buf 0, A=aE), step 25 (buf 1, A=aO) ------------------
  loadA(25, aO);
  __builtin_amdgcn_sched_barrier(0);
  write_X(1, s1);                      // x(25) loaded at step 23
  mfma_phase(0, aE);
  barrier();
  mfma_phase(1, aO);

  // ---- epilogue: rows wave*48 + mtl*16 + l4*4, col p0 + nt*16 + l15 --------
#pragma unroll
  for (int mtl = 0; mtl < 3; ++mtl) {
    int mrow0 = wave * 48 + mtl * 16 + l4 * 4;   // r0 in {0,4,8} -> same d
    int d  = mrow0 / 12;
    int r0 = mrow0 - d * 12;
#pragma unroll
    for (int nt = 0; nt < 4; ++nt) {
      int p = p0 + nt * 16 + l15;
      float* dst = out + (size_t)((b * 16 + d) * 4096 + p) * 12 + r0;
      *(f32x4*)dst = acc[mtl][nt];               // 16B aligned
    }
  }
}

// ---------------------------------------------------------------------------
extern "C" void kernel_launch(void* const* d_in, const int* in_sizes, int n_in,
                              void* d_out, int out_size, void* d_ws, size_t ws_size,
                              hipStream_t stream) {
  const float* x       = (const float*)d_in[0];  // (8,16,13,4096,12) f32
  const float* W       = (const float*)d_in[1];  // (16,16,36) f32
  const int*   idx_map = (const int*)d_in[2];    // (156,)
  const int*   tivr    = (const int*)d_in[3];    // (12,13)
  const int*   tir     = (const int*)d_in[4];    // (12,12)
  float*       out     = (float*)d_out;          // (8,16,4096,12) f32
  __bf16*      WmatF   = (__bf16*)d_ws;          // 936 KB, fragment-ordered

  build_wmatf<<<dim3(117), dim3(512), 0, stream>>>(W, idx_map, tivr, tir, WmatF);
  s2conv<<<dim3(512), dim3(256), 0, stream>>>(x, WmatF, out);
}